// Round 19
// baseline (55.453 us; speedup 1.0000x reference)
//
#include <hip/hip_runtime.h>
#include <math.h>

#define H_   16
#define NB_  64
#define D_   1024
#define HID_ 64
#define B_   4
#define T_   2048
#define ROWS (B_*T_)    // 8192
#define HNB  (H_*NB_)   // 1024

typedef short v8s __attribute__((ext_vector_type(8)));
typedef float v4f __attribute__((ext_vector_type(4)));

__device__ __forceinline__ float gelu_exact(float x) {
    return 0.5f * x * (1.0f + erff(x * 0.7071067811865476f));
}
__device__ __forceinline__ float sigmoidf(float x) {
    return 1.0f / (1.0f + expf(-x));
}
__device__ __forceinline__ ushort f2bf(float x) {   // RNE float->bf16 bits
    union { float f; unsigned u; } v; v.f = x;
    unsigned r = v.u + 0x7fffu + ((v.u >> 16) & 1u);
    return (ushort)(r >> 16);
}

// ------- Kernel 0: prep. blk<16: W1(1024x64 f32)->w1t(64x1024 bf16);
//                   blk>=16: W2(64x1024 f32)->w2t(1024x64 bf16). -------
__global__ __launch_bounds__(256) void k_prep(const float* __restrict__ W1,
                                              const float* __restrict__ W2,
                                              ushort* __restrict__ w1t,
                                              ushort* __restrict__ w2t) {
    __shared__ float ls[64][65];
    const int t   = threadIdx.x;
    const int blk = blockIdx.x;
    if (blk < 16) {
        const int k0 = blk * 64;
        #pragma unroll
        for (int q = 0; q < 4; ++q) {
            int idx = q * 256 + t;
            int r = idx >> 4, c4 = idx & 15;
            *(float4*)&ls[r][c4 * 4] =
                *(const float4*)&W1[(size_t)(k0 + r) * 64 + c4 * 4];
        }
        __syncthreads();
        const int col = t >> 2, kq = t & 3;
        ushort out[16];
        #pragma unroll
        for (int e = 0; e < 16; ++e) out[e] = f2bf(ls[kq * 16 + e][col]);
        *(uint4*)&w1t[(size_t)col * 1024 + k0 + kq * 16]     = *(uint4*)&out[0];
        *(uint4*)&w1t[(size_t)col * 1024 + k0 + kq * 16 + 8] = *(uint4*)&out[8];
    } else {
        const int n0 = (blk - 16) * 64;
        #pragma unroll
        for (int q = 0; q < 4; ++q) {
            int idx = q * 256 + t;
            int r = idx >> 4, c4 = idx & 15;    // r = k (0..63)
            *(float4*)&ls[r][c4 * 4] =
                *(const float4*)&W2[(size_t)r * HNB + n0 + c4 * 4];
        }
        __syncthreads();
        const int n = t >> 2, kq = t & 3;
        ushort out[16];
        #pragma unroll
        for (int e = 0; e < 16; ++e) out[e] = f2bf(ls[kq * 16 + e][n]);
        *(uint4*)&w2t[(size_t)(n0 + n) * 64 + kq * 16]     = *(uint4*)&out[0];
        *(uint4*)&w2t[(size_t)(n0 + n) * 64 + kq * 16 + 8] = *(uint4*)&out[8];
    }
}

// ------- Kernel 1: h(bf16) = gelu(X @ W1 + b1), MFMA, BM=16, grid 512 -------
__global__ __launch_bounds__(256) void k_gemm1_mfma(const float* __restrict__ X,
                                                    const ushort* __restrict__ w1t,
                                                    const float* __restrict__ b1,
                                                    ushort* __restrict__ hbuf) {
    __shared__ ushort Al[16 * 128];     // 4 KiB
    __shared__ ushort Bl[64 * 128];     // 16 KiB
    const int t    = threadIdx.x;
    const int r0   = blockIdx.x * 16;
    const int w    = t >> 6;
    const int lane = t & 63;
    const int lo   = lane & 15;
    const int hi   = lane >> 4;
    const int arow = t >> 4, aseg = t & 15;  // A stage: 16 rows x 16 segs(8k)
    const int brow = t >> 2, bseg = t & 3;   // B stage: 64 rows x 4 segs(32k)

    v4f acc = {0.f,0.f,0.f,0.f};

    for (int c = 0; c < 8; ++c) {
        float xv[8];
        const float* xp = &X[(size_t)(r0 + arow) * D_ + c * 128 + aseg * 8];
        *(float4*)&xv[0] = *(const float4*)&xp[0];
        *(float4*)&xv[4] = *(const float4*)&xp[4];
        ushort wv[32];
        const ushort* wp = &w1t[(size_t)brow * 1024 + c * 128 + bseg * 32];
        #pragma unroll
        for (int i = 0; i < 4; ++i) *(uint4*)&wv[i*8] = *(const uint4*)&wp[i*8];

        __syncthreads();
        {
            const int k = aseg * 8;
            union { ushort u[8]; v8s v; } pa;
            #pragma unroll
            for (int e = 0; e < 8; ++e) pa.u[e] = f2bf(xv[e]);
            *(v8s*)&Al[arow * 128 + (k ^ ((arow & 7) << 3))] = pa.v;
        }
        #pragma unroll
        for (int j8 = 0; j8 < 4; ++j8) {
            const int k = bseg * 32 + j8 * 8;
            *(v8s*)&Bl[brow * 128 + (k ^ ((brow & 7) << 3))] = *(v8s*)&wv[j8 * 8];
        }
        __syncthreads();

        #pragma unroll
        for (int kk = 0; kk < 4; ++kk) {
            const int k  = kk * 32 + hi * 8;
            const int sw = k ^ ((lo & 7) << 3);
            v8s af = *(v8s*)&Al[lo * 128 + sw];
            v8s bf = *(v8s*)&Bl[(w * 16 + lo) * 128 + sw];
            acc = __builtin_amdgcn_mfma_f32_16x16x32_bf16(af, bf, acc, 0, 0, 0);
        }
    }
    const int col = w * 16 + lo;
    const float bb = b1[col];
    #pragma unroll
    for (int j = 0; j < 4; ++j) {
        const int row = r0 + hi * 4 + j;
        hbuf[(size_t)row * HID_ + col] = f2bf(gelu_exact(acc[j] + bb));
    }
}

// ------- Kernel 2: gates = sigmoid(h @ W2 + b2), MFMA, tile 64x256 -------
// Also writes bf16 sidecar gbf (for the BW-bound scan) when gbf != nullptr.
__global__ __launch_bounds__(256) void k_gemm2_mfma(const ushort* __restrict__ hbuf,
                                                    const ushort* __restrict__ w2t,
                                                    const float* __restrict__ b2,
                                                    float* __restrict__ gates,
                                                    ushort* __restrict__ gbf) {
    __shared__ ushort Ah[64 * 64];
    __shared__ ushort Bh[256 * 64];
    const int t    = threadIdx.x;
    const int r0   = (blockIdx.x >> 2) * 64;
    const int n0   = (blockIdx.x & 3) * 256;
    const int w    = t >> 6;
    const int lane = t & 63;
    const int lo   = lane & 15;
    const int hi   = lane >> 4;

    {
        const int row = t >> 2, seg = t & 3;
        uint4 v0 = *(const uint4*)&hbuf[(size_t)(r0 + row) * 64 + seg * 16];
        uint4 v1 = *(const uint4*)&hbuf[(size_t)(r0 + row) * 64 + seg * 16 + 8];
        const int sw = (row & 7) << 3;
        *(uint4*)&Ah[row * 64 + ((seg * 16) ^ sw)]     = v0;
        *(uint4*)&Ah[row * 64 + ((seg * 16 + 8) ^ sw)] = v1;
    }
    #pragma unroll
    for (int q = 0; q < 4; ++q) {
        const int pi  = q * 256 + t;
        const int n   = pi >> 2, seg = pi & 3;
        uint4 v0 = *(const uint4*)&w2t[(size_t)(n0 + n) * 64 + seg * 16];
        uint4 v1 = *(const uint4*)&w2t[(size_t)(n0 + n) * 64 + seg * 16 + 8];
        const int sw = (n & 7) << 3;
        *(uint4*)&Bh[n * 64 + ((seg * 16) ^ sw)]     = v0;
        *(uint4*)&Bh[n * 64 + ((seg * 16 + 8) ^ sw)] = v1;
    }
    __syncthreads();

    v4f acc[4][4];
    #pragma unroll
    for (int mt = 0; mt < 4; ++mt)
        #pragma unroll
        for (int nt = 0; nt < 4; ++nt) acc[mt][nt] = (v4f){0.f,0.f,0.f,0.f};

    #pragma unroll
    for (int kc = 0; kc < 2; ++kc) {
        const int k  = kc * 32 + hi * 8;
        const int sw = k ^ ((lo & 7) << 3);
        v8s af[4];
        #pragma unroll
        for (int mt = 0; mt < 4; ++mt)
            af[mt] = *(v8s*)&Ah[(mt * 16 + lo) * 64 + sw];
        #pragma unroll
        for (int nt = 0; nt < 4; ++nt) {
            v8s bf = *(v8s*)&Bh[(w * 64 + nt * 16 + lo) * 64 + sw];
            #pragma unroll
            for (int mt = 0; mt < 4; ++mt)
                acc[mt][nt] = __builtin_amdgcn_mfma_f32_16x16x32_bf16(af[mt], bf, acc[mt][nt], 0, 0, 0);
        }
    }

    #pragma unroll
    for (int nt = 0; nt < 4; ++nt) {
        const int col = n0 + w * 64 + nt * 16 + lo;
        const float bb = b2[col];
        #pragma unroll
        for (int mt = 0; mt < 4; ++mt) {
            #pragma unroll
            for (int j = 0; j < 4; ++j) {
                const int row = r0 + mt * 16 + hi * 4 + j;
                float gv = sigmoidf(acc[mt][nt][j] + bb);
                gates[(size_t)row * HNB + col] = gv;
                if (gbf) gbf[(size_t)row * HNB + col] = f2bf(gv);
            }
        }
    }
}

// ------- Kernel 3: segmented 4-wave scan, XCD-swizzled, bf16-gates --------
// R17 structure (SEGK=8, TT=32, WARMT=2, raw barriers, reg-staged loaders).
// New: (a) block swizzle groups all 8 segs of one bh onto one XCD (warmup
// tiles re-read neighbor-seg data -> L2 hits); (b) wave2 reads gates from
// the bf16 sidecar (half the bytes off the BW-bound kernel).
#define TT_    32
#define SEGK   8
#define SEGLEN (T_/SEGK)   // 256
#define WARMT  2           // warmup tiles = 64 steps

#define PHASE_SYNC() { \
    asm volatile("s_waitcnt lgkmcnt(0)" ::: "memory"); \
    __builtin_amdgcn_s_barrier(); \
    asm volatile("" ::: "memory"); }

#define LD8(A, G, grp) { \
    _Pragma("unroll") \
    for (int u = 0; u < 8; ++u) { \
        A[u] = pa[((grp)*8 + u) * 128]; \
        G[u] = pa[((grp)*8 + u) * 128 + 64]; \
    } }

#define CP8(A, G, grp) { \
    _Pragma("unroll") \
    for (int u = 0; u < 8; ++u) { \
        float a   = A[u]; \
        float omg = G[u]; \
        float aR  = a + R; \
        float pc  = fmaf(omg, a, R); \
        float den = sigma + aR; \
        float s   = sigma + a; \
        float pp  = fmaf(omg, sigma, pc); \
        float rc  = __builtin_amdgcn_rcpf(den); \
        float tt  = s * pp; \
        sigma     = tt * rc; \
        ps[((grp)*8 + u) * 64] = sigma; \
    } }

#define DLOAD(tile) { \
    const int t0_ = tstart + (tile) * TT_; \
    _Pragma("unroll") \
    for (int it = 0; it < 8; ++it) \
        dreg[it] = *(const float4*)&dp[(size_t)(t0_ + it * 4 + rg) * HNB]; }

#define GLOAD(tile) { \
    const int t0_ = tstart + (tile) * TT_; \
    _Pragma("unroll") \
    for (int it = 0; it < 4; ++it) \
        greg[it] = *(const uint4*)&gp2[(size_t)(t0_ + it * 8 + rg8) * HNB]; }

__global__ __launch_bounds__(256) void k_scan_seg6(
        const float* __restrict__ delta,
        const ushort* __restrict__ gbf,
        const float* __restrict__ omega,
        const float* __restrict__ log_Q,
        const float* __restrict__ log_R,
        const float* __restrict__ log_s0,
        float* __restrict__ sig) {
    __shared__ float tg_lds[2][TT_][2][64];   // a-plane / (1-g)-plane, 32 KiB
    __shared__ float sg_lds[2][TT_][64];      // 16 KiB
    const int tid = threadIdx.x;
    const int blk = blockIdx.x;
    // XCD swizzle: all 8 segs of a bh land on one XCD (blk%8 = XCD model)
    const int bh  = (blk & 7) * 8 + (blk >> 6);   // 0..63
    const int seg = (blk >> 3) & 7;
    const int b   = bh >> 4;
    const int h   = bh & 15;
    const size_t base = (size_t)b * T_ * HNB + h * NB_;
    const int wv   = tid >> 6;
    const int lane = tid & 63;

    const int warm   = (seg == 0) ? 0 : WARMT;
    const int ntiles = SEGLEN / TT_ + warm;          // 8 or 10
    const int tstart = seg * SEGLEN - warm * TT_;

    float R = 0.f, sigma = 0.f;
    float sc0=0,sc1=0,sc2=0,sc3=0;
    const int col4 = lane & 15;
    const int rg   = lane >> 4;
    const int col8 = lane & 7;     // wave2: 16B bf16 chunk
    const int rg8  = lane >> 3;    // wave2: row group 0..7
    const float* dp = 0;
    const ushort* gp2 = 0;
    float4 dreg[8];
    uint4  greg[4];

    if (wv == 0) {
        const int hn = h * NB_ + lane;
        R     = expf(log_R[hn]);
        sigma = expf(log_s0[hn]);   // exact for seg 0; warmup guess otherwise
    } else if (wv == 1) {
        const int hn4 = h * NB_ + col4 * 4;
        float4 om4 = *(const float4*)&omega[hn4];
        float4 lq4 = *(const float4*)&log_Q[hn4];
        sc0 = expf(lq4.x) * om4.x * om4.x;
        sc1 = expf(lq4.y) * om4.y * om4.y;
        sc2 = expf(lq4.z) * om4.z * om4.z;
        sc3 = expf(lq4.w) * om4.w * om4.w;
        dp = delta + base + col4 * 4;
        DLOAD(0);                       // prologue: tile 0 -> regs
    } else if (wv == 2) {
        gp2 = gbf + base + col8 * 8;
        GLOAD(0);
    }

    for (int p = 0; p <= ntiles + 1; ++p) {
        if (wv == 0) {
            if (p >= 1 && p <= ntiles) {
                const int buf = (p - 1) & 1;
                const float* pa = &tg_lds[buf][0][0][lane];
                float*       ps = &sg_lds[buf][0][lane];
                float a0[8], g0[8], a1[8], g1[8];
                LD8(a0, g0, 0);
                LD8(a1, g1, 1);
                CP8(a0, g0, 0); LD8(a0, g0, 2);
                CP8(a1, g1, 1); LD8(a1, g1, 3);
                CP8(a0, g0, 2);
                CP8(a1, g1, 3);
            }
        } else if (wv == 1) {
            if (p < ntiles) {
                const int buf = p & 1;
                #pragma unroll
                for (int it = 0; it < 8; ++it) {
                    const int row = it * 4 + rg;
                    float4 d = dreg[it];
                    float4 a;
                    a.x = (sc0 * d.x) * d.x;
                    a.y = (sc1 * d.y) * d.y;
                    a.z = (sc2 * d.z) * d.z;
                    a.w = (sc3 * d.w) * d.w;
                    *(float4*)&tg_lds[buf][row][0][col4 * 4] = a;
                }
                if (p + 1 < ntiles) DLOAD(p + 1);   // issue next tile's loads
            }
        } else if (wv == 2) {
            if (p < ntiles) {
                const int buf = p & 1;
                #pragma unroll
                for (int it = 0; it < 4; ++it) {
                    const int row = it * 8 + rg8;
                    unsigned uu[4] = {greg[it].x, greg[it].y, greg[it].z, greg[it].w};
                    float o[8];
                    #pragma unroll
                    for (int j = 0; j < 4; ++j) {
                        union { unsigned u; float f; } c;
                        c.u = uu[j] << 16;          o[2*j]   = 1.0f - c.f;
                        c.u = uu[j] & 0xffff0000u;  o[2*j+1] = 1.0f - c.f;
                    }
                    *(float4*)&tg_lds[buf][row][1][col8 * 8]     = *(float4*)&o[0];
                    *(float4*)&tg_lds[buf][row][1][col8 * 8 + 4] = *(float4*)&o[4];
                }
                if (p + 1 < ntiles) GLOAD(p + 1);
            }
        } else {
            const int tile = p - 2;
            if (tile >= warm && tile < ntiles) {
                const int buf = p & 1;
                const int t0  = tstart + tile * TT_;
                float* op = sig + base + col4 * 4;
                #pragma unroll
                for (int it = 0; it < 8; ++it) {
                    const int row = it * 4 + rg;
                    float4 v = *(const float4*)&sg_lds[buf][row][col4 * 4];
                    *(float4*)&op[(size_t)(t0 + row) * HNB] = v;
                }
            }
        }
        PHASE_SYNC();
    }
}

// ---------- Fallback scan (fp32 gates, R17), used only when ws too small ----
__global__ __launch_bounds__(256) void k_scan_seg4(
        const float* __restrict__ delta,
        const float* __restrict__ gates,
        const float* __restrict__ omega,
        const float* __restrict__ log_Q,
        const float* __restrict__ log_R,
        const float* __restrict__ log_s0,
        float* __restrict__ sig) {
    __shared__ float tg_lds[2][TT_][2][64];
    __shared__ float sg_lds[2][TT_][64];
    const int tid = threadIdx.x;
    const int blk = blockIdx.x;
    const int bh  = blk >> 3;
    const int seg = blk & 7;
    const int b   = bh >> 4;
    const int h   = bh & 15;
    const size_t base = (size_t)b * T_ * HNB + h * NB_;
    const int wv   = tid >> 6;
    const int lane = tid & 63;

    const int warm   = (seg == 0) ? 0 : WARMT;
    const int ntiles = SEGLEN / TT_ + warm;
    const int tstart = seg * SEGLEN - warm * TT_;

    float R = 0.f, sigma = 0.f;
    float sc0=0,sc1=0,sc2=0,sc3=0;
    const int col4 = lane & 15;
    const int rg   = lane >> 4;
    const float* dp = 0;
    float4 dreg[8];

    if (wv == 0) {
        const int hn = h * NB_ + lane;
        R     = expf(log_R[hn]);
        sigma = expf(log_s0[hn]);
    } else if (wv == 1) {
        const int hn4 = h * NB_ + col4 * 4;
        float4 om4 = *(const float4*)&omega[hn4];
        float4 lq4 = *(const float4*)&log_Q[hn4];
        sc0 = expf(lq4.x) * om4.x * om4.x;
        sc1 = expf(lq4.y) * om4.y * om4.y;
        sc2 = expf(lq4.z) * om4.z * om4.z;
        sc3 = expf(lq4.w) * om4.w * om4.w;
        dp = delta + base + col4 * 4;
        DLOAD(0);
    } else if (wv == 2) {
        dp = gates + base + col4 * 4;
        DLOAD(0);
    }

    for (int p = 0; p <= ntiles + 1; ++p) {
        if (wv == 0) {
            if (p >= 1 && p <= ntiles) {
                const int buf = (p - 1) & 1;
                const float* pa = &tg_lds[buf][0][0][lane];
                float*       ps = &sg_lds[buf][0][lane];
                float a0[8], g0[8], a1[8], g1[8];
                LD8(a0, g0, 0);
                LD8(a1, g1, 1);
                CP8(a0, g0, 0); LD8(a0, g0, 2);
                CP8(a1, g1, 1); LD8(a1, g1, 3);
                CP8(a0, g0, 2);
                CP8(a1, g1, 3);
            }
        } else if (wv == 1) {
            if (p < ntiles) {
                const int buf = p & 1;
                #pragma unroll
                for (int it = 0; it < 8; ++it) {
                    const int row = it * 4 + rg;
                    float4 d = dreg[it];
                    float4 a;
                    a.x = (sc0 * d.x) * d.x;
                    a.y = (sc1 * d.y) * d.y;
                    a.z = (sc2 * d.z) * d.z;
                    a.w = (sc3 * d.w) * d.w;
                    *(float4*)&tg_lds[buf][row][0][col4 * 4] = a;
                }
                if (p + 1 < ntiles) DLOAD(p + 1);
            }
        } else if (wv == 2) {
            if (p < ntiles) {
                const int buf = p & 1;
                #pragma unroll
                for (int it = 0; it < 8; ++it) {
                    const int row = it * 4 + rg;
                    float4 g = dreg[it];
                    float4 o;
                    o.x = 1.0f - g.x; o.y = 1.0f - g.y;
                    o.z = 1.0f - g.z; o.w = 1.0f - g.w;
                    *(float4*)&tg_lds[buf][row][1][col4 * 4] = o;
                }
                if (p + 1 < ntiles) DLOAD(p + 1);
            }
        } else {
            const int tile = p - 2;
            if (tile >= warm && tile < ntiles) {
                const int buf = p & 1;
                const int t0  = tstart + tile * TT_;
                float* op = sig + base + col4 * 4;
                #pragma unroll
                for (int it = 0; it < 8; ++it) {
                    const int row = it * 4 + rg;
                    float4 v = *(const float4*)&sg_lds[buf][row][col4 * 4];
                    *(float4*)&op[(size_t)(t0 + row) * HNB] = v;
                }
            }
        }
        PHASE_SYNC();
    }
}

extern "C" void kernel_launch(void* const* d_in, const int* in_sizes, int n_in,
                              void* d_out, int out_size, void* d_ws, size_t ws_size,
                              hipStream_t stream) {
    const float* delta   = (const float*)d_in[0];
    const float* content = (const float*)d_in[1];
    const float* omega   = (const float*)d_in[2];
    const float* log_Q   = (const float*)d_in[3];
    const float* log_R   = (const float*)d_in[4];
    const float* log_s0  = (const float*)d_in[5];
    const float* W1      = (const float*)d_in[6];
    const float* b1      = (const float*)d_in[7];
    const float* W2      = (const float*)d_in[8];
    const float* b2      = (const float*)d_in[9];

    float* sig_out   = (float*)d_out;                    // 8388608 floats
    float* gates_out = sig_out + (size_t)ROWS * HNB;     // next 8388608

    const size_t n_h   = (size_t)ROWS * HID_;            // 524288 bf16
    const size_t n_w1t = (size_t)HID_ * D_;              // 65536 bf16
    const size_t n_w2t = (size_t)HNB * HID_;             // 65536 bf16
    const size_t n_gbf = (size_t)ROWS * HNB;             // 8388608 bf16 (16.8 MB)
    const size_t need_full = (n_h + n_w1t + n_w2t + n_gbf) * sizeof(ushort);
    const size_t need_min  = (n_h + n_w1t + n_w2t) * sizeof(ushort);

    if (ws_size >= need_full) {
        ushort* hbuf = (ushort*)d_ws;
        ushort* w1t  = hbuf + n_h;
        ushort* w2t  = w1t + n_w1t;
        ushort* gbf  = w2t + n_w2t;
        k_prep<<<32, 256, 0, stream>>>(W1, W2, w1t, w2t);
        k_gemm1_mfma<<<ROWS / 16, 256, 0, stream>>>(content, w1t, b1, hbuf);
        k_gemm2_mfma<<<(ROWS / 64) * 4, 256, 0, stream>>>(hbuf, w2t, b2,
                                                          gates_out, gbf);
        k_scan_seg6<<<B_ * H_ * SEGK, 256, 0, stream>>>(delta, gbf, omega,
                                                        log_Q, log_R, log_s0,
                                                        sig_out);
    } else {
        ushort* hbuf = (ws_size >= need_min) ? (ushort*)d_ws : (ushort*)sig_out;
        ushort* w1t  = hbuf + n_h;
        ushort* w2t  = w1t + n_w1t;
        k_prep<<<32, 256, 0, stream>>>(W1, W2, w1t, w2t);
        k_gemm1_mfma<<<ROWS / 16, 256, 0, stream>>>(content, w1t, b1, hbuf);
        k_gemm2_mfma<<<(ROWS / 64) * 4, 256, 0, stream>>>(hbuf, w2t, b2,
                                                          gates_out, nullptr);
        k_scan_seg4<<<B_ * H_ * SEGK, 256, 0, stream>>>(delta, gates_out, omega,
                                                        log_Q, log_R, log_s0,
                                                        sig_out);
    }
}

// Round 20
// 54.788 us; speedup vs baseline: 1.0121x; 1.0121x over previous
//
#include <hip/hip_runtime.h>
#include <math.h>

#define H_   16
#define NB_  64
#define D_   1024
#define HID_ 64
#define B_   4
#define T_   2048
#define ROWS (B_*T_)    // 8192
#define HNB  (H_*NB_)   // 1024

typedef short v8s __attribute__((ext_vector_type(8)));
typedef float v4f __attribute__((ext_vector_type(4)));

__device__ __forceinline__ float gelu_exact(float x) {
    return 0.5f * x * (1.0f + erff(x * 0.7071067811865476f));
}
__device__ __forceinline__ float sigmoidf(float x) {
    return 1.0f / (1.0f + expf(-x));
}
__device__ __forceinline__ ushort f2bf(float x) {   // RNE float->bf16 bits
    union { float f; unsigned u; } v; v.f = x;
    unsigned r = v.u + 0x7fffu + ((v.u >> 16) & 1u);
    return (ushort)(r >> 16);
}

// ------- Kernel 0: prep. blk<16: W1(1024x64 f32)->w1t(64x1024 bf16);
//                   blk>=16: W2(64x1024 f32)->w2t(1024x64 bf16). -------
__global__ __launch_bounds__(256) void k_prep(const float* __restrict__ W1,
                                              const float* __restrict__ W2,
                                              ushort* __restrict__ w1t,
                                              ushort* __restrict__ w2t) {
    __shared__ float ls[64][65];
    const int t   = threadIdx.x;
    const int blk = blockIdx.x;
    if (blk < 16) {
        const int k0 = blk * 64;
        #pragma unroll
        for (int q = 0; q < 4; ++q) {
            int idx = q * 256 + t;
            int r = idx >> 4, c4 = idx & 15;
            *(float4*)&ls[r][c4 * 4] =
                *(const float4*)&W1[(size_t)(k0 + r) * 64 + c4 * 4];
        }
        __syncthreads();
        const int col = t >> 2, kq = t & 3;
        ushort out[16];
        #pragma unroll
        for (int e = 0; e < 16; ++e) out[e] = f2bf(ls[kq * 16 + e][col]);
        *(uint4*)&w1t[(size_t)col * 1024 + k0 + kq * 16]     = *(uint4*)&out[0];
        *(uint4*)&w1t[(size_t)col * 1024 + k0 + kq * 16 + 8] = *(uint4*)&out[8];
    } else {
        const int n0 = (blk - 16) * 64;
        #pragma unroll
        for (int q = 0; q < 4; ++q) {
            int idx = q * 256 + t;
            int r = idx >> 4, c4 = idx & 15;    // r = k (0..63)
            *(float4*)&ls[r][c4 * 4] =
                *(const float4*)&W2[(size_t)r * HNB + n0 + c4 * 4];
        }
        __syncthreads();
        const int n = t >> 2, kq = t & 3;
        ushort out[16];
        #pragma unroll
        for (int e = 0; e < 16; ++e) out[e] = f2bf(ls[kq * 16 + e][n]);
        *(uint4*)&w2t[(size_t)(n0 + n) * 64 + kq * 16]     = *(uint4*)&out[0];
        *(uint4*)&w2t[(size_t)(n0 + n) * 64 + kq * 16 + 8] = *(uint4*)&out[8];
    }
}

// ------- Kernel 1: h(bf16) = gelu(X @ W1 + b1), MFMA, BM=16, grid 512 -------
__global__ __launch_bounds__(256) void k_gemm1_mfma(const float* __restrict__ X,
                                                    const ushort* __restrict__ w1t,
                                                    const float* __restrict__ b1,
                                                    ushort* __restrict__ hbuf) {
    __shared__ ushort Al[16 * 128];     // 4 KiB
    __shared__ ushort Bl[64 * 128];     // 16 KiB
    const int t    = threadIdx.x;
    const int r0   = blockIdx.x * 16;
    const int w    = t >> 6;
    const int lane = t & 63;
    const int lo   = lane & 15;
    const int hi   = lane >> 4;
    const int arow = t >> 4, aseg = t & 15;  // A stage: 16 rows x 16 segs(8k)
    const int brow = t >> 2, bseg = t & 3;   // B stage: 64 rows x 4 segs(32k)

    v4f acc = {0.f,0.f,0.f,0.f};

    for (int c = 0; c < 8; ++c) {
        float xv[8];
        const float* xp = &X[(size_t)(r0 + arow) * D_ + c * 128 + aseg * 8];
        *(float4*)&xv[0] = *(const float4*)&xp[0];
        *(float4*)&xv[4] = *(const float4*)&xp[4];
        ushort wv[32];
        const ushort* wp = &w1t[(size_t)brow * 1024 + c * 128 + bseg * 32];
        #pragma unroll
        for (int i = 0; i < 4; ++i) *(uint4*)&wv[i*8] = *(const uint4*)&wp[i*8];

        __syncthreads();
        {
            const int k = aseg * 8;
            union { ushort u[8]; v8s v; } pa;
            #pragma unroll
            for (int e = 0; e < 8; ++e) pa.u[e] = f2bf(xv[e]);
            *(v8s*)&Al[arow * 128 + (k ^ ((arow & 7) << 3))] = pa.v;
        }
        #pragma unroll
        for (int j8 = 0; j8 < 4; ++j8) {
            const int k = bseg * 32 + j8 * 8;
            *(v8s*)&Bl[brow * 128 + (k ^ ((brow & 7) << 3))] = *(v8s*)&wv[j8 * 8];
        }
        __syncthreads();

        #pragma unroll
        for (int kk = 0; kk < 4; ++kk) {
            const int k  = kk * 32 + hi * 8;
            const int sw = k ^ ((lo & 7) << 3);
            v8s af = *(v8s*)&Al[lo * 128 + sw];
            v8s bf = *(v8s*)&Bl[(w * 16 + lo) * 128 + sw];
            acc = __builtin_amdgcn_mfma_f32_16x16x32_bf16(af, bf, acc, 0, 0, 0);
        }
    }
    const int col = w * 16 + lo;
    const float bb = b1[col];
    #pragma unroll
    for (int j = 0; j < 4; ++j) {
        const int row = r0 + hi * 4 + j;
        hbuf[(size_t)row * HID_ + col] = f2bf(gelu_exact(acc[j] + bb));
    }
}

// ------- Kernel 2: gates = sigmoid(h @ W2 + b2), MFMA, tile 64x256 -------
__global__ __launch_bounds__(256) void k_gemm2_mfma(const ushort* __restrict__ hbuf,
                                                    const ushort* __restrict__ w2t,
                                                    const float* __restrict__ b2,
                                                    float* __restrict__ gates) {
    __shared__ ushort Ah[64 * 64];
    __shared__ ushort Bh[256 * 64];
    const int t    = threadIdx.x;
    const int r0   = (blockIdx.x >> 2) * 64;
    const int n0   = (blockIdx.x & 3) * 256;
    const int w    = t >> 6;
    const int lane = t & 63;
    const int lo   = lane & 15;
    const int hi   = lane >> 4;

    {
        const int row = t >> 2, seg = t & 3;
        uint4 v0 = *(const uint4*)&hbuf[(size_t)(r0 + row) * 64 + seg * 16];
        uint4 v1 = *(const uint4*)&hbuf[(size_t)(r0 + row) * 64 + seg * 16 + 8];
        const int sw = (row & 7) << 3;
        *(uint4*)&Ah[row * 64 + ((seg * 16) ^ sw)]     = v0;
        *(uint4*)&Ah[row * 64 + ((seg * 16 + 8) ^ sw)] = v1;
    }
    #pragma unroll
    for (int q = 0; q < 4; ++q) {
        const int pi  = q * 256 + t;
        const int n   = pi >> 2, seg = pi & 3;
        uint4 v0 = *(const uint4*)&w2t[(size_t)(n0 + n) * 64 + seg * 16];
        uint4 v1 = *(const uint4*)&w2t[(size_t)(n0 + n) * 64 + seg * 16 + 8];
        const int sw = (n & 7) << 3;
        *(uint4*)&Bh[n * 64 + ((seg * 16) ^ sw)]     = v0;
        *(uint4*)&Bh[n * 64 + ((seg * 16 + 8) ^ sw)] = v1;
    }
    __syncthreads();

    v4f acc[4][4];
    #pragma unroll
    for (int mt = 0; mt < 4; ++mt)
        #pragma unroll
        for (int nt = 0; nt < 4; ++nt) acc[mt][nt] = (v4f){0.f,0.f,0.f,0.f};

    #pragma unroll
    for (int kc = 0; kc < 2; ++kc) {
        const int k  = kc * 32 + hi * 8;
        const int sw = k ^ ((lo & 7) << 3);
        v8s af[4];
        #pragma unroll
        for (int mt = 0; mt < 4; ++mt)
            af[mt] = *(v8s*)&Ah[(mt * 16 + lo) * 64 + sw];
        #pragma unroll
        for (int nt = 0; nt < 4; ++nt) {
            v8s bf = *(v8s*)&Bh[(w * 64 + nt * 16 + lo) * 64 + sw];
            #pragma unroll
            for (int mt = 0; mt < 4; ++mt)
                acc[mt][nt] = __builtin_amdgcn_mfma_f32_16x16x32_bf16(af[mt], bf, acc[mt][nt], 0, 0, 0);
        }
    }

    #pragma unroll
    for (int nt = 0; nt < 4; ++nt) {
        const int col = n0 + w * 64 + nt * 16 + lo;
        const float bb = b2[col];
        #pragma unroll
        for (int mt = 0; mt < 4; ++mt) {
            #pragma unroll
            for (int j = 0; j < 4; ++j) {
                const int row = r0 + mt * 16 + hi * 4 + j;
                gates[(size_t)row * HNB + col] = sigmoidf(acc[mt][nt][j] + bb);
            }
        }
    }
}

// ------- Kernel 3: segmented 4-wave scan (R17 structure) + XCD swizzle -----
// SEGK=8, TT=32, WARMT=2, raw barriers, reg-staged loaders. Swizzle: all 8
// segments of one (b,h) map to consecutive blk%8 values -> same XCD under
// round-robin dispatch, so warmup re-reads hit that XCD's L2.
#define TT_    32
#define SEGK   8
#define SEGLEN (T_/SEGK)   // 256
#define WARMT  2           // warmup tiles = 64 steps

#define PHASE_SYNC() { \
    asm volatile("s_waitcnt lgkmcnt(0)" ::: "memory"); \
    __builtin_amdgcn_s_barrier(); \
    asm volatile("" ::: "memory"); }

#define LD8(A, G, grp) { \
    _Pragma("unroll") \
    for (int u = 0; u < 8; ++u) { \
        A[u] = pa[((grp)*8 + u) * 128]; \
        G[u] = pa[((grp)*8 + u) * 128 + 64]; \
    } }

#define CP8(A, G, grp) { \
    _Pragma("unroll") \
    for (int u = 0; u < 8; ++u) { \
        float a   = A[u]; \
        float omg = G[u]; \
        float aR  = a + R; \
        float pc  = fmaf(omg, a, R); \
        float den = sigma + aR; \
        float s   = sigma + a; \
        float pp  = fmaf(omg, sigma, pc); \
        float rc  = __builtin_amdgcn_rcpf(den); \
        float tt  = s * pp; \
        sigma     = tt * rc; \
        ps[((grp)*8 + u) * 64] = sigma; \
    } }

#define DLOAD(tile) { \
    const int t0_ = tstart + (tile) * TT_; \
    _Pragma("unroll") \
    for (int it = 0; it < 8; ++it) \
        dreg[it] = *(const float4*)&dp[(size_t)(t0_ + it * 4 + rg) * HNB]; }

__global__ __launch_bounds__(256) void k_scan_seg4(
        const float* __restrict__ delta,
        const float* __restrict__ gates,
        const float* __restrict__ omega,
        const float* __restrict__ log_Q,
        const float* __restrict__ log_R,
        const float* __restrict__ log_s0,
        float* __restrict__ sig) {
    __shared__ float tg_lds[2][TT_][2][64];   // a-plane / (1-g)-plane, 32 KiB
    __shared__ float sg_lds[2][TT_][64];      // 16 KiB
    const int tid = threadIdx.x;
    const int blk = blockIdx.x;
    // XCD swizzle: segs of one bh at blk = bh/8*64 + seg*8 + bh%8
    // -> blk%8 constant per bh-group of 8; all 8 segs of bh on one XCD.
    const int bh  = (blk >> 6) * 8 + (blk & 7);   // 0..63
    const int seg = (blk >> 3) & 7;
    const int b   = bh >> 4;
    const int h   = bh & 15;
    const size_t base = (size_t)b * T_ * HNB + h * NB_;
    const int wv   = tid >> 6;
    const int lane = tid & 63;

    const int warm   = (seg == 0) ? 0 : WARMT;
    const int ntiles = SEGLEN / TT_ + warm;          // 8 or 10
    const int tstart = seg * SEGLEN - warm * TT_;

    float R = 0.f, sigma = 0.f;
    float sc0=0,sc1=0,sc2=0,sc3=0;
    const int col4 = lane & 15;
    const int rg   = lane >> 4;
    const float* dp = 0;
    float4 dreg[8];

    if (wv == 0) {
        const int hn = h * NB_ + lane;
        R     = expf(log_R[hn]);
        sigma = expf(log_s0[hn]);   // exact for seg 0; warmup guess otherwise
    } else if (wv == 1) {
        const int hn4 = h * NB_ + col4 * 4;
        float4 om4 = *(const float4*)&omega[hn4];
        float4 lq4 = *(const float4*)&log_Q[hn4];
        sc0 = expf(lq4.x) * om4.x * om4.x;
        sc1 = expf(lq4.y) * om4.y * om4.y;
        sc2 = expf(lq4.z) * om4.z * om4.z;
        sc3 = expf(lq4.w) * om4.w * om4.w;
        dp = delta + base + col4 * 4;
        DLOAD(0);                       // prologue: tile 0 -> regs
    } else if (wv == 2) {
        dp = gates + base + col4 * 4;
        DLOAD(0);
    }

    for (int p = 0; p <= ntiles + 1; ++p) {
        if (wv == 0) {
            if (p >= 1 && p <= ntiles) {
                const int buf = (p - 1) & 1;
                const float* pa = &tg_lds[buf][0][0][lane];
                float*       ps = &sg_lds[buf][0][lane];
                float a0[8], g0[8], a1[8], g1[8];
                LD8(a0, g0, 0);
                LD8(a1, g1, 1);
                CP8(a0, g0, 0); LD8(a0, g0, 2);
                CP8(a1, g1, 1); LD8(a1, g1, 3);
                CP8(a0, g0, 2);
                CP8(a1, g1, 3);
            }
        } else if (wv == 1) {
            if (p < ntiles) {
                const int buf = p & 1;
                #pragma unroll
                for (int it = 0; it < 8; ++it) {
                    const int row = it * 4 + rg;
                    float4 d = dreg[it];
                    float4 a;
                    a.x = (sc0 * d.x) * d.x;
                    a.y = (sc1 * d.y) * d.y;
                    a.z = (sc2 * d.z) * d.z;
                    a.w = (sc3 * d.w) * d.w;
                    *(float4*)&tg_lds[buf][row][0][col4 * 4] = a;
                }
                if (p + 1 < ntiles) DLOAD(p + 1);   // issue next tile's loads
            }
        } else if (wv == 2) {
            if (p < ntiles) {
                const int buf = p & 1;
                #pragma unroll
                for (int it = 0; it < 8; ++it) {
                    const int row = it * 4 + rg;
                    float4 g = dreg[it];
                    float4 o;
                    o.x = 1.0f - g.x; o.y = 1.0f - g.y;
                    o.z = 1.0f - g.z; o.w = 1.0f - g.w;
                    *(float4*)&tg_lds[buf][row][1][col4 * 4] = o;
                }
                if (p + 1 < ntiles) DLOAD(p + 1);
            }
        } else {
            const int tile = p - 2;
            if (tile >= warm && tile < ntiles) {
                const int buf = p & 1;
                const int t0  = tstart + tile * TT_;
                float* op = sig + base + col4 * 4;
                #pragma unroll
                for (int it = 0; it < 8; ++it) {
                    const int row = it * 4 + rg;
                    float4 v = *(const float4*)&sg_lds[buf][row][col4 * 4];
                    *(float4*)&op[(size_t)(t0 + row) * HNB] = v;
                }
            }
        }
        PHASE_SYNC();
    }
}

extern "C" void kernel_launch(void* const* d_in, const int* in_sizes, int n_in,
                              void* d_out, int out_size, void* d_ws, size_t ws_size,
                              hipStream_t stream) {
    const float* delta   = (const float*)d_in[0];
    const float* content = (const float*)d_in[1];
    const float* omega   = (const float*)d_in[2];
    const float* log_Q   = (const float*)d_in[3];
    const float* log_R   = (const float*)d_in[4];
    const float* log_s0  = (const float*)d_in[5];
    const float* W1      = (const float*)d_in[6];
    const float* b1      = (const float*)d_in[7];
    const float* W2      = (const float*)d_in[8];
    const float* b2      = (const float*)d_in[9];

    float* sig_out   = (float*)d_out;                    // 8388608 floats
    float* gates_out = sig_out + (size_t)ROWS * HNB;     // next 8388608

    const size_t n_h   = (size_t)ROWS * HID_;            // 524288 bf16
    const size_t n_w1t = (size_t)HID_ * D_;              // 65536 bf16
    const size_t n_w2t = (size_t)HNB * HID_;             // 65536 bf16
    const size_t need  = (n_h + n_w1t + n_w2t) * sizeof(ushort);

    ushort *hbuf, *w1t, *w2t;
    if (ws_size >= need) {
        hbuf = (ushort*)d_ws;
    } else {
        hbuf = (ushort*)sig_out;   // scratch in sigma region (overwritten by scan)
    }
    w1t = hbuf + n_h;
    w2t = w1t + n_w1t;

    k_prep<<<32, 256, 0, stream>>>(W1, W2, w1t, w2t);
    k_gemm1_mfma<<<ROWS / 16, 256, 0, stream>>>(content, w1t, b1, hbuf);
    k_gemm2_mfma<<<(ROWS / 64) * 4, 256, 0, stream>>>(hbuf, w2t, b2, gates_out);
    k_scan_seg4<<<B_ * H_ * SEGK, 256, 0, stream>>>(delta, gates_out, omega,
                                                    log_Q, log_R, log_s0, sig_out);
}